// Round 2
// baseline (114.640 us; speedup 1.0000x reference)
//
#include <hip/hip_runtime.h>
#include <hip/hip_fp16.h>

// WordGraphNet fp32. Round 15: read-once edge sort.
// - Revert round-14 column split (latency-bound, not L2-capacity-bound:
//   VALU 24%, HBM 15%, Mfma 0.7% -> split only added loop overhead).
// - Fill now also builds a GLOBAL fine histogram gfine[50048] (8 random
//   L2 atomics/thread). Coarse buckets shrink to 128 nodes (dst>>7, 391
//   buckets) so one sort block = one bucket = the 128 agg1 groups.
// - Sort kernel loads its 128-bin gfine slice (1 coalesced read), scans,
//   scatters: epack is read ONCE instead of 4x (2 half-blocks x hist+
//   scatter). Kills ~28MB of HBM fetch + 2 serial barrier phases in the
//   slowest dispatch (was 38MB FETCH, 41us).
// Pipeline: memset | fill+gemm1 | sort+agg1+gemm2 | agg2.  (~60us of total
// is harness ws-poison/restore, visible as the only top-5 entries.)

#define N_NODES 50000
#define N_EDGES 1200000
#define IN_SIZE 128
#define HID 64
#define NEG_SLOPE 0.01f
#define NBB 391           // buckets of 128 nodes: ceil(50000/128)
#define SLOTC 3456        // slots/bucket (mean 3070, sigma 55 -> +7 sigma)
#define FILL_EPB 8192
#define FILL_BLOCKS ((N_EDGES + FILL_EPB - 1) / FILL_EPB)   // 147
#define GEMM_BLOCKS ((N_NODES + 255) / 256)                 // 196
#define RS2 (HID + 8)     // padded LDS row stride (72 halves = 144B)

typedef _Float16 half8 __attribute__((ext_vector_type(8)));
typedef float floatx4 __attribute__((ext_vector_type(4)));

// ---------------- MFMA GEMM body (1024 thr, 256 rows/blk), fp32 A -----------
template <int K>
__device__ __forceinline__ void gemm_body(int blk,
                                          const float* __restrict__ A,
                                          const float* __restrict__ W,
                                          const float* __restrict__ b,
                                          _Float16* __restrict__ out,
                                          _Float16* wthi, _Float16* wtlo) {
    constexpr int RS = K + 8;
    const int tid = threadIdx.x;
    for (int i = tid; i < 64 * K; i += 1024) {
        int n = i / K, k = i % K;
        float wv = W[k * 64 + n];
        _Float16 hi = (_Float16)wv;
        wthi[n * RS + k] = hi;
        wtlo[n * RS + k] = (_Float16)(wv - (float)hi);
    }
    __syncthreads();

    const int lane = tid & 63;
    const int wid = tid >> 6;
    const int q = lane >> 4, c = lane & 15;

    int arow = blk * 256 + wid * 16 + c;
    int lrow = min(arow, N_NODES - 1);
    const float* ap = A + (size_t)lrow * K + q * 8;

    floatx4 acc0 = {b[c],      b[c],      b[c],      b[c]};
    floatx4 acc1 = {b[c + 16], b[c + 16], b[c + 16], b[c + 16]};
    floatx4 acc2 = {b[c + 32], b[c + 32], b[c + 32], b[c + 32]};
    floatx4 acc3 = {b[c + 48], b[c + 48], b[c + 48], b[c + 48]};

#pragma unroll
    for (int ks = 0; ks < K / 32; ++ks) {
        float4 f0 = ((const float4*)(ap + ks * 32))[0];
        float4 f1 = ((const float4*)(ap + ks * 32))[1];
        float fv[8] = {f0.x, f0.y, f0.z, f0.w, f1.x, f1.y, f1.z, f1.w};
        half8 ahi, alo;
#pragma unroll
        for (int j = 0; j < 8; ++j) {
            _Float16 h = (_Float16)fv[j];
            ahi[j] = h;
            alo[j] = (_Float16)(fv[j] - (float)h);
        }
        const int kb = ks * 32 + q * 8;
        half8 bh0 = *(const half8*)&wthi[(c     ) * RS + kb];
        half8 bl0 = *(const half8*)&wtlo[(c     ) * RS + kb];
        half8 bh1 = *(const half8*)&wthi[(c + 16) * RS + kb];
        half8 bl1 = *(const half8*)&wtlo[(c + 16) * RS + kb];
        half8 bh2 = *(const half8*)&wthi[(c + 32) * RS + kb];
        half8 bl2 = *(const half8*)&wtlo[(c + 32) * RS + kb];
        half8 bh3 = *(const half8*)&wthi[(c + 48) * RS + kb];
        half8 bl3 = *(const half8*)&wtlo[(c + 48) * RS + kb];
        acc0 = __builtin_amdgcn_mfma_f32_16x16x32_f16(ahi, bh0, acc0, 0, 0, 0);
        acc0 = __builtin_amdgcn_mfma_f32_16x16x32_f16(ahi, bl0, acc0, 0, 0, 0);
        acc0 = __builtin_amdgcn_mfma_f32_16x16x32_f16(alo, bh0, acc0, 0, 0, 0);
        acc1 = __builtin_amdgcn_mfma_f32_16x16x32_f16(ahi, bh1, acc1, 0, 0, 0);
        acc1 = __builtin_amdgcn_mfma_f32_16x16x32_f16(ahi, bl1, acc1, 0, 0, 0);
        acc1 = __builtin_amdgcn_mfma_f32_16x16x32_f16(alo, bh1, acc1, 0, 0, 0);
        acc2 = __builtin_amdgcn_mfma_f32_16x16x32_f16(ahi, bh2, acc2, 0, 0, 0);
        acc2 = __builtin_amdgcn_mfma_f32_16x16x32_f16(ahi, bl2, acc2, 0, 0, 0);
        acc2 = __builtin_amdgcn_mfma_f32_16x16x32_f16(alo, bh2, acc2, 0, 0, 0);
        acc3 = __builtin_amdgcn_mfma_f32_16x16x32_f16(ahi, bh3, acc3, 0, 0, 0);
        acc3 = __builtin_amdgcn_mfma_f32_16x16x32_f16(ahi, bl3, acc3, 0, 0, 0);
        acc3 = __builtin_amdgcn_mfma_f32_16x16x32_f16(alo, bh3, acc3, 0, 0, 0);
    }

    int rowb = blk * 256 + wid * 16 + q * 4;
#pragma unroll
    for (int r = 0; r < 4; ++r) {
        if (rowb + r < N_NODES) {
            _Float16* op = out + (size_t)(rowb + r) * HID + c;
            op[0]  = (_Float16)acc0[r];
            op[16] = (_Float16)acc1[r];
            op[32] = (_Float16)acc2[r];
            op[48] = (_Float16)acc3[r];
        }
    }
}

// ---------------- fill body: 8192 edges, 391 coarse bins, 1024 thr ----------
// Also accumulates the global fine histogram gfine[node] (L2 atomics).
__device__ __forceinline__ void fill_body(int blk,
                                          const int* __restrict__ src,
                                          const int* __restrict__ dst,
                                          const float* __restrict__ ew,
                                          int* __restrict__ gcur,
                                          int* __restrict__ gfine,
                                          int2* __restrict__ epack,
                                          int* lhist, int* lbase) {
    const int tid = threadIdx.x;
    const int e0 = blk * FILL_EPB;
    if (tid < NBB) lhist[tid] = 0;

    const int g0 = e0 + 4 * tid, g1 = g0 + 4096;
    const bool a0 = g0 < N_EDGES, a1 = g1 < N_EDGES;
    int4 d0 = {0,0,0,0}, d1 = {0,0,0,0}, s0 = {0,0,0,0}, s1 = {0,0,0,0};
    float4 w0 = {0,0,0,0}, w1 = {0,0,0,0};
    if (a0) { d0 = *(const int4*)(dst + g0); s0 = *(const int4*)(src + g0);
              w0 = *(const float4*)(ew + g0); }
    if (a1) { d1 = *(const int4*)(dst + g1); s1 = *(const int4*)(src + g1);
              w1 = *(const float4*)(ew + g1); }
    __syncthreads();

    if (a0) { atomicAdd(&lhist[d0.x >> 7], 1); atomicAdd(&lhist[d0.y >> 7], 1);
              atomicAdd(&lhist[d0.z >> 7], 1); atomicAdd(&lhist[d0.w >> 7], 1); }
    if (a1) { atomicAdd(&lhist[d1.x >> 7], 1); atomicAdd(&lhist[d1.y >> 7], 1);
              atomicAdd(&lhist[d1.z >> 7], 1); atomicAdd(&lhist[d1.w >> 7], 1); }
    __syncthreads();

    if (tid < NBB) {
        int c = lhist[tid];
        lbase[tid] = tid * SLOTC + (c ? atomicAdd(&gcur[tid], c) : 0);
        lhist[tid] = 0;                      // reuse as local cursor
    }
    __syncthreads();

    const int dd0[4] = {d0.x, d0.y, d0.z, d0.w};
    const int ss0[4] = {s0.x, s0.y, s0.z, s0.w};
    const float ww0[4] = {w0.x, w0.y, w0.z, w0.w};
    const int dd1[4] = {d1.x, d1.y, d1.z, d1.w};
    const int ss1[4] = {s1.x, s1.y, s1.z, s1.w};
    const float ww1[4] = {w1.x, w1.y, w1.z, w1.w};
    if (a0) {
#pragma unroll
        for (int j = 0; j < 4; ++j) {
            int d = dd0[j], b = d >> 7;
            int idx = lbase[b] + atomicAdd(&lhist[b], 1);
            if (idx < (b + 1) * SLOTC)       // 7-sigma guard, never taken
                epack[idx] = make_int2(ss0[j] | ((d & 127) << 16),
                                       __float_as_int(ww0[j]));
            atomicAdd(&gfine[d], 1);         // fine hist (L2-resident 200KB)
        }
    }
    if (a1) {
#pragma unroll
        for (int j = 0; j < 4; ++j) {
            int d = dd1[j], b = d >> 7;
            int idx = lbase[b] + atomicAdd(&lhist[b], 1);
            if (idx < (b + 1) * SLOTC)
                epack[idx] = make_int2(ss1[j] | ((d & 127) << 16),
                                       __float_as_int(ww1[j]));
            atomicAdd(&gfine[d], 1);
        }
    }
}

// ---------------- fused dispatch: fill (0..146) + gemm1 (147..342) ----------
__global__ __launch_bounds__(1024) void fill_gemm1(const int* __restrict__ src,
                                                   const int* __restrict__ dst,
                                                   const float* __restrict__ ew,
                                                   int* __restrict__ gcur,
                                                   int* __restrict__ gfine,
                                                   int2* __restrict__ epack,
                                                   const float* __restrict__ x,
                                                   const float* __restrict__ W1,
                                                   const float* __restrict__ b1,
                                                   _Float16* __restrict__ outA) {
    __shared__ union SU {
        struct { int lhist[NBB]; int lbase[NBB]; } f;
        struct { _Float16 hi[64 * (IN_SIZE + 8)];
                 _Float16 lo[64 * (IN_SIZE + 8)]; } g;
    } u;
    if (blockIdx.x < FILL_BLOCKS)
        fill_body(blockIdx.x, src, dst, ew, gcur, gfine, epack,
                  u.f.lhist, u.f.lbase);
    else
        gemm_body<IN_SIZE>(blockIdx.x - FILL_BLOCKS, x, W1, b1, outA,
                           u.g.hi, u.g.lo);
}

// ---------------- fused sort + agg1 + gemm2 (block = 128-node bucket) -------
// Phase S: load 128-bin gfine slice -> scan (off written for agg2) ->
//          scatter bucket to lsort (epack read ONCE) -> stream to esort.
// Phase A: group-per-node (16 waves x 8 groups = 128 nodes exactly); per edge:
//          8-lane-broadcast ds_read of lsort + 16B Wh1 gather + 8 fma.
// Phase G: Wh2[128,64] = h1_tile @ W2 + b2 (fp16 A exact, hi/lo W2).
__global__ __launch_bounds__(1024) void sort_agg1_gemm2(
        const int* __restrict__ gcur, const int* __restrict__ gfine,
        const int2* __restrict__ epack,
        const _Float16* __restrict__ Wh1,
        const float* __restrict__ W2, const float* __restrict__ b2,
        unsigned int* __restrict__ esort, int* __restrict__ off,
        _Float16* __restrict__ outB) {
    __shared__ unsigned int lsort[SLOTC];     // 13.5 KB
    __shared__ int cnt[128];
    __shared__ int start[128];
    __shared__ int wsum[2];
    __shared__ _Float16 w2hi[64 * RS2];       // 9.2 KB
    __shared__ _Float16 w2lo[64 * RS2];       // 9.2 KB
    __shared__ _Float16 hs[128 * RS2];        // 18 KB h1 tile
    const int tid = threadIdx.x;
    const int bkt = blockIdx.x;
    const int beg = bkt * SLOTC;
    const int n = min(gcur[bkt], SLOTC);

    // stage W2 transposed hi/lo (overlaps hist load)
    for (int i = tid; i < 64 * HID; i += 1024) {
        int nn = i >> 6, k = i & 63;
        float wv = W2[k * 64 + nn];
        _Float16 hi = (_Float16)wv;
        w2hi[nn * RS2 + k] = hi;
        w2lo[nn * RS2 + k] = (_Float16)(wv - (float)hi);
    }
    if (tid < 128) cnt[tid] = gfine[bkt * 128 + tid];
    __syncthreads();
    int orig = 0, incl = 0;
    if (tid < 128) {
        orig = cnt[tid];
        int v = orig;
        for (int o = 1; o < 64; o <<= 1) {
            int t = __shfl_up(v, o);
            if ((tid & 63) >= o) v += t;
        }
        if ((tid & 63) == 63) wsum[tid >> 6] = v;
        incl = v;
    }
    __syncthreads();
    if (tid < 128) {
        if (tid >= 64) incl += wsum[0];
        int excl = incl - orig;
        start[tid] = excl;
        off[bkt * 129 + tid] = beg + excl;
        if (tid == 127) off[bkt * 129 + 128] = beg + incl;
        cnt[tid] = 0;                          // reuse as cursor
    }
    __syncthreads();
    for (int e = tid; e < n; e += 1024) {
        int2 pk = epack[beg + e];
        int d7 = (pk.x >> 16) & 127;
        int pos = atomicAdd(&cnt[d7], 1);
        int idx = start[d7] + pos;
        unsigned short hw = __half_as_ushort(__float2half(__int_as_float(pk.y)));
        if (idx < SLOTC)
            lsort[idx] = (unsigned int)(pk.x & 0xffff) | ((unsigned int)hw << 16);
    }
    __syncthreads();
    // stream to esort for agg2 (coalesced)
    for (int i = tid; i < n; i += 1024)
        esort[beg + i] = lsort[i];

    // Phase A: aggregate from LDS. group nl handles local node nl.
    {
        const int lane = tid & 63;
        const int g = lane >> 3, p = lane & 7;
        const int nl = (tid >> 6) * 8 + g;    // 0..127
        const int lbeg = start[nl];
        const int deg = cnt[nl];              // cursor == bin count
        float acc[8] = {0, 0, 0, 0, 0, 0, 0, 0};
        const int lend = min(lbeg + deg, SLOTC);
        for (int e = lbeg; e < lend; ++e) {
            const unsigned int pe = lsort[e]; // 8-lane broadcast read
            const float w =
                __half2float(__ushort_as_half((unsigned short)(pe >> 16)));
            half8 row = *(const half8*)(Wh1 + (size_t)(pe & 0xffff) * HID + p * 8);
#pragma unroll
            for (int j = 0; j < 8; ++j)
                acc[j] = fmaf((float)row[j], w, acc[j]);
        }
        const float inv = 1.0f / fmaxf((float)deg, 1.0f);
        half8 hv;
#pragma unroll
        for (int j = 0; j < 8; ++j) {
            float t = acc[j] * inv;
            t = t >= 0.0f ? t : NEG_SLOPE * t;   // leaky relu
            hv[j] = (_Float16)t;
        }
        *(half8*)&hs[nl * RS2 + p * 8] = hv;
    }
    __syncthreads();

    // Phase G: gemm2. wave w: row-tile r = w>>1 (16 rows), col half ch = w&1.
    {
        const int lane = tid & 63, wid = tid >> 6;
        const int q = lane >> 4, c = lane & 15;
        const int r = wid >> 1, ch = wid & 1;
        floatx4 acc0 = {b2[ch * 32 + c], b2[ch * 32 + c],
                        b2[ch * 32 + c], b2[ch * 32 + c]};
        floatx4 acc1 = {b2[ch * 32 + 16 + c], b2[ch * 32 + 16 + c],
                        b2[ch * 32 + 16 + c], b2[ch * 32 + 16 + c]};
#pragma unroll
        for (int ks = 0; ks < 2; ++ks) {
            const int kb = ks * 32 + q * 8;
            half8 a = *(const half8*)&hs[(r * 16 + c) * RS2 + kb];
            half8 bh0 = *(const half8*)&w2hi[(ch * 32 + c) * RS2 + kb];
            half8 bl0 = *(const half8*)&w2lo[(ch * 32 + c) * RS2 + kb];
            half8 bh1 = *(const half8*)&w2hi[(ch * 32 + 16 + c) * RS2 + kb];
            half8 bl1 = *(const half8*)&w2lo[(ch * 32 + 16 + c) * RS2 + kb];
            acc0 = __builtin_amdgcn_mfma_f32_16x16x32_f16(a, bh0, acc0, 0, 0, 0);
            acc0 = __builtin_amdgcn_mfma_f32_16x16x32_f16(a, bl0, acc0, 0, 0, 0);
            acc1 = __builtin_amdgcn_mfma_f32_16x16x32_f16(a, bh1, acc1, 0, 0, 0);
            acc1 = __builtin_amdgcn_mfma_f32_16x16x32_f16(a, bl1, acc1, 0, 0, 0);
        }
        const int rowb = bkt * 128 + r * 16 + q * 4;
#pragma unroll
        for (int rr = 0; rr < 4; ++rr) {
            if (rowb + rr < N_NODES) {
                _Float16* op = outB + (size_t)(rowb + rr) * HID + ch * 32 + c;
                op[0]  = (_Float16)acc0[rr];
                op[16] = (_Float16)acc1[rr];
            }
        }
    }
}

// ---------------- agg2 (group-per-node, shfl payloads) ----------------------
__global__ __launch_bounds__(256) void agg2_k(const _Float16* __restrict__ Wh,
                                              const int* __restrict__ off,
                                              const unsigned int* __restrict__ es,
                                              float* __restrict__ out) {
    const int tid = threadIdx.x;
    const int lane = tid & 63;
    const int wid = tid >> 6;
    const int g = lane >> 3, p = lane & 7;
    const int node = blockIdx.x * 32 + wid * 8 + g;
    const bool valid = node < N_NODES;
    int beg = 0, end = 0;
    if (valid) {
        const int o = (node >> 7) * 129 + (node & 127);
        beg = off[o];
        end = off[o + 1];
    }
    const int deg = end - beg;

    unsigned int pld[5];
#pragma unroll
    for (int c = 0; c < 5; ++c) {
        int e = beg + c * 8 + p;
        pld[c] = (e < end) ? es[e] : 0u;
    }

    int mdeg = deg;
#pragma unroll
    for (int mask = 8; mask <= 32; mask <<= 1)
        mdeg = max(mdeg, __shfl_xor(mdeg, mask));

    float acc[8] = {0, 0, 0, 0, 0, 0, 0, 0};
#pragma unroll
    for (int c = 0; c < 5; ++c) {
        if (c * 8 >= mdeg) break;
#pragma unroll
        for (int s = 0; s < 8; ++s) {
            const unsigned int pe = __shfl(pld[c], (g << 3) | s);
            const bool act = beg + c * 8 + s < end;
            const int srow = act ? (int)(pe & 0xffff) : 0;   // row 0: L1-hot
            const float w = act
                ? __half2float(__ushort_as_half((unsigned short)(pe >> 16)))
                : 0.0f;
            half8 row = *(const half8*)(Wh + (size_t)srow * HID + p * 8);
#pragma unroll
            for (int j = 0; j < 8; ++j)
                acc[j] = fmaf((float)row[j], w, acc[j]);
        }
    }
    for (int e = beg + 40; e < end; ++e) {    // rare tail (P ~ 8e-4)
        const unsigned int pe = es[e];
        const float w =
            __half2float(__ushort_as_half((unsigned short)(pe >> 16)));
        half8 row = *(const half8*)(Wh + (size_t)(pe & 0xffff) * HID + p * 8);
#pragma unroll
        for (int j = 0; j < 8; ++j)
            acc[j] = fmaf((float)row[j], w, acc[j]);
    }

    if (valid) {
        const float inv = 1.0f / fmaxf((float)deg, 1.0f);
        float4* op = (float4*)(out + (size_t)node * HID + p * 8);
        op[0] = make_float4(acc[0] * inv, acc[1] * inv, acc[2] * inv, acc[3] * inv);
        op[1] = make_float4(acc[4] * inv, acc[5] * inv, acc[6] * inv, acc[7] * inv);
    }
}

extern "C" void kernel_launch(void* const* d_in, const int* in_sizes, int n_in,
                              void* d_out, int out_size, void* d_ws, size_t ws_size,
                              hipStream_t stream) {
    const float* x  = (const float*)d_in[0];
    const float* ew = (const float*)d_in[1];
    const float* W1 = (const float*)d_in[2];
    const float* b1 = (const float*)d_in[3];
    const float* W2 = (const float*)d_in[4];
    const float* b2 = (const float*)d_in[5];
    const int* src  = (const int*)d_in[6];
    const int* dst  = (const int*)d_in[7];
    float* out = (float*)d_out;

    const int NH = N_NODES * HID;
    const int ES = NBB * SLOTC;                             // 1,351,296

    // ws layout (~28 MB):
    // gcur(400) | gfine(50048) | off(391*129+1 pad 50448) | esort u32 |
    // epack int2 | bufA (Wh1) | bufB (Wh2)
    int* gcur = (int*)d_ws;                                 // 391 (+pad 400)
    int* gfine = gcur + 400;                                // 50048
    int* off  = gfine + 50048;                              // 50440 (+pad)
    unsigned int* esort = (unsigned int*)(off + 50448);     // ES u32 (5.4 MB)
    int2* epack = (int2*)(esort + ES);                      // ES int2 (10.8 MB)
    _Float16* bufA = (_Float16*)(epack + ES);               // Wh1 (6.4 MB)
    _Float16* bufB = bufA + NH;                             // Wh2 (6.4 MB)

    const int agg2Blocks = (N_NODES + 31) / 32;             // 1563

    // zero gcur + gfine in one shot (contiguous, ~202 KB)
    hipMemsetAsync(gcur, 0, (400 + 50048) * sizeof(int), stream);

    // fill + gemm1 fused (independent inputs)
    fill_gemm1<<<FILL_BLOCKS + GEMM_BLOCKS, 1024, 0, stream>>>(
        src, dst, ew, gcur, gfine, epack, x, W1, b1, bufA);

    // sort + agg1 + gemm2 fused (block = 128-node bucket) -> esort/off + Wh2
    sort_agg1_gemm2<<<NBB, 1024, 0, stream>>>(
        gcur, gfine, epack, bufA, W2, b2, esort, off, bufB);

    // final aggregation
    agg2_k<<<agg2Blocks, 256, 0, stream>>>(bufB, off, esort, out);
}

// Round 3
// 76.902 us; speedup vs baseline: 1.4907x; 1.4907x over previous
//
#include <hip/hip_runtime.h>
#include <hip/hip_fp16.h>

// WordGraphNet fp32. Round 16: read-once sort WITHOUT global fine hist.
// R15 post-mortem: gfine's 1.2M random global atomics stalled fill_gemm1
// (30->61.6us, VALU 2.7%). Revert fill to R13 form. Instead the sort block
// builds the fine hist while STAGING its bucket into LDS in one pass over
// epack (pay u32 + d7 u8 + LDS atomic hist from registers), then scans and
// scatters entirely from LDS. epack is still read exactly ONCE from global
// (R15's win) but the hist is free (R13's fill cost).
// 128-node buckets (391), one 1024-thr block per bucket = 128 agg1 groups.
// Pipeline: memset(1.6KB) | fill+gemm1 | sort+agg1+gemm2 | agg2.

#define N_NODES 50000
#define N_EDGES 1200000
#define IN_SIZE 128
#define HID 64
#define NEG_SLOPE 0.01f
#define NBB 391           // buckets of 128 nodes: ceil(50000/128)
#define SLOTC 3456        // slots/bucket (mean 3070, sigma 55 -> +7 sigma)
#define FILL_EPB 8192
#define FILL_BLOCKS ((N_EDGES + FILL_EPB - 1) / FILL_EPB)   // 147
#define GEMM_BLOCKS ((N_NODES + 255) / 256)                 // 196
#define RS2 (HID + 8)     // padded LDS row stride (72 halves = 144B)

typedef _Float16 half8 __attribute__((ext_vector_type(8)));
typedef float floatx4 __attribute__((ext_vector_type(4)));

// ---------------- MFMA GEMM body (1024 thr, 256 rows/blk), fp32 A -----------
template <int K>
__device__ __forceinline__ void gemm_body(int blk,
                                          const float* __restrict__ A,
                                          const float* __restrict__ W,
                                          const float* __restrict__ b,
                                          _Float16* __restrict__ out,
                                          _Float16* wthi, _Float16* wtlo) {
    constexpr int RS = K + 8;
    const int tid = threadIdx.x;
    for (int i = tid; i < 64 * K; i += 1024) {
        int n = i / K, k = i % K;
        float wv = W[k * 64 + n];
        _Float16 hi = (_Float16)wv;
        wthi[n * RS + k] = hi;
        wtlo[n * RS + k] = (_Float16)(wv - (float)hi);
    }
    __syncthreads();

    const int lane = tid & 63;
    const int wid = tid >> 6;
    const int q = lane >> 4, c = lane & 15;

    int arow = blk * 256 + wid * 16 + c;
    int lrow = min(arow, N_NODES - 1);
    const float* ap = A + (size_t)lrow * K + q * 8;

    floatx4 acc0 = {b[c],      b[c],      b[c],      b[c]};
    floatx4 acc1 = {b[c + 16], b[c + 16], b[c + 16], b[c + 16]};
    floatx4 acc2 = {b[c + 32], b[c + 32], b[c + 32], b[c + 32]};
    floatx4 acc3 = {b[c + 48], b[c + 48], b[c + 48], b[c + 48]};

#pragma unroll
    for (int ks = 0; ks < K / 32; ++ks) {
        float4 f0 = ((const float4*)(ap + ks * 32))[0];
        float4 f1 = ((const float4*)(ap + ks * 32))[1];
        float fv[8] = {f0.x, f0.y, f0.z, f0.w, f1.x, f1.y, f1.z, f1.w};
        half8 ahi, alo;
#pragma unroll
        for (int j = 0; j < 8; ++j) {
            _Float16 h = (_Float16)fv[j];
            ahi[j] = h;
            alo[j] = (_Float16)(fv[j] - (float)h);
        }
        const int kb = ks * 32 + q * 8;
        half8 bh0 = *(const half8*)&wthi[(c     ) * RS + kb];
        half8 bl0 = *(const half8*)&wtlo[(c     ) * RS + kb];
        half8 bh1 = *(const half8*)&wthi[(c + 16) * RS + kb];
        half8 bl1 = *(const half8*)&wtlo[(c + 16) * RS + kb];
        half8 bh2 = *(const half8*)&wthi[(c + 32) * RS + kb];
        half8 bl2 = *(const half8*)&wtlo[(c + 32) * RS + kb];
        half8 bh3 = *(const half8*)&wthi[(c + 48) * RS + kb];
        half8 bl3 = *(const half8*)&wtlo[(c + 48) * RS + kb];
        acc0 = __builtin_amdgcn_mfma_f32_16x16x32_f16(ahi, bh0, acc0, 0, 0, 0);
        acc0 = __builtin_amdgcn_mfma_f32_16x16x32_f16(ahi, bl0, acc0, 0, 0, 0);
        acc0 = __builtin_amdgcn_mfma_f32_16x16x32_f16(alo, bh0, acc0, 0, 0, 0);
        acc1 = __builtin_amdgcn_mfma_f32_16x16x32_f16(ahi, bh1, acc1, 0, 0, 0);
        acc1 = __builtin_amdgcn_mfma_f32_16x16x32_f16(ahi, bl1, acc1, 0, 0, 0);
        acc1 = __builtin_amdgcn_mfma_f32_16x16x32_f16(alo, bh1, acc1, 0, 0, 0);
        acc2 = __builtin_amdgcn_mfma_f32_16x16x32_f16(ahi, bh2, acc2, 0, 0, 0);
        acc2 = __builtin_amdgcn_mfma_f32_16x16x32_f16(ahi, bl2, acc2, 0, 0, 0);
        acc2 = __builtin_amdgcn_mfma_f32_16x16x32_f16(alo, bh2, acc2, 0, 0, 0);
        acc3 = __builtin_amdgcn_mfma_f32_16x16x32_f16(ahi, bh3, acc3, 0, 0, 0);
        acc3 = __builtin_amdgcn_mfma_f32_16x16x32_f16(ahi, bl3, acc3, 0, 0, 0);
        acc3 = __builtin_amdgcn_mfma_f32_16x16x32_f16(alo, bh3, acc3, 0, 0, 0);
    }

    int rowb = blk * 256 + wid * 16 + q * 4;
#pragma unroll
    for (int r = 0; r < 4; ++r) {
        if (rowb + r < N_NODES) {
            _Float16* op = out + (size_t)(rowb + r) * HID + c;
            op[0]  = (_Float16)acc0[r];
            op[16] = (_Float16)acc1[r];
            op[32] = (_Float16)acc2[r];
            op[48] = (_Float16)acc3[r];
        }
    }
}

// ---------------- fill body: 8192 edges, 391 coarse bins, 1024 thr ----------
__device__ __forceinline__ void fill_body(int blk,
                                          const int* __restrict__ src,
                                          const int* __restrict__ dst,
                                          const float* __restrict__ ew,
                                          int* __restrict__ gcur,
                                          int2* __restrict__ epack,
                                          int* lhist, int* lbase) {
    const int tid = threadIdx.x;
    const int e0 = blk * FILL_EPB;
    if (tid < NBB) lhist[tid] = 0;

    const int g0 = e0 + 4 * tid, g1 = g0 + 4096;
    const bool a0 = g0 < N_EDGES, a1 = g1 < N_EDGES;
    int4 d0 = {0,0,0,0}, d1 = {0,0,0,0}, s0 = {0,0,0,0}, s1 = {0,0,0,0};
    float4 w0 = {0,0,0,0}, w1 = {0,0,0,0};
    if (a0) { d0 = *(const int4*)(dst + g0); s0 = *(const int4*)(src + g0);
              w0 = *(const float4*)(ew + g0); }
    if (a1) { d1 = *(const int4*)(dst + g1); s1 = *(const int4*)(src + g1);
              w1 = *(const float4*)(ew + g1); }
    __syncthreads();

    if (a0) { atomicAdd(&lhist[d0.x >> 7], 1); atomicAdd(&lhist[d0.y >> 7], 1);
              atomicAdd(&lhist[d0.z >> 7], 1); atomicAdd(&lhist[d0.w >> 7], 1); }
    if (a1) { atomicAdd(&lhist[d1.x >> 7], 1); atomicAdd(&lhist[d1.y >> 7], 1);
              atomicAdd(&lhist[d1.z >> 7], 1); atomicAdd(&lhist[d1.w >> 7], 1); }
    __syncthreads();

    if (tid < NBB) {
        int c = lhist[tid];
        lbase[tid] = tid * SLOTC + (c ? atomicAdd(&gcur[tid], c) : 0);
        lhist[tid] = 0;                      // reuse as local cursor
    }
    __syncthreads();

    const int dd0[4] = {d0.x, d0.y, d0.z, d0.w};
    const int ss0[4] = {s0.x, s0.y, s0.z, s0.w};
    const float ww0[4] = {w0.x, w0.y, w0.z, w0.w};
    const int dd1[4] = {d1.x, d1.y, d1.z, d1.w};
    const int ss1[4] = {s1.x, s1.y, s1.z, s1.w};
    const float ww1[4] = {w1.x, w1.y, w1.z, w1.w};
    if (a0) {
#pragma unroll
        for (int j = 0; j < 4; ++j) {
            int d = dd0[j], b = d >> 7;
            int idx = lbase[b] + atomicAdd(&lhist[b], 1);
            if (idx < (b + 1) * SLOTC)       // 7-sigma guard, never taken
                epack[idx] = make_int2(ss0[j] | ((d & 127) << 16),
                                       __float_as_int(ww0[j]));
        }
    }
    if (a1) {
#pragma unroll
        for (int j = 0; j < 4; ++j) {
            int d = dd1[j], b = d >> 7;
            int idx = lbase[b] + atomicAdd(&lhist[b], 1);
            if (idx < (b + 1) * SLOTC)
                epack[idx] = make_int2(ss1[j] | ((d & 127) << 16),
                                       __float_as_int(ww1[j]));
        }
    }
}

// ---------------- fused dispatch: fill (0..146) + gemm1 (147..342) ----------
__global__ __launch_bounds__(1024) void fill_gemm1(const int* __restrict__ src,
                                                   const int* __restrict__ dst,
                                                   const float* __restrict__ ew,
                                                   int* __restrict__ gcur,
                                                   int2* __restrict__ epack,
                                                   const float* __restrict__ x,
                                                   const float* __restrict__ W1,
                                                   const float* __restrict__ b1,
                                                   _Float16* __restrict__ outA) {
    __shared__ union SU {
        struct { int lhist[NBB]; int lbase[NBB]; } f;
        struct { _Float16 hi[64 * (IN_SIZE + 8)];
                 _Float16 lo[64 * (IN_SIZE + 8)]; } g;
    } u;
    if (blockIdx.x < FILL_BLOCKS)
        fill_body(blockIdx.x, src, dst, ew, gcur, epack,
                  u.f.lhist, u.f.lbase);
    else
        gemm_body<IN_SIZE>(blockIdx.x - FILL_BLOCKS, x, W1, b1, outA,
                           u.g.hi, u.g.lo);
}

// ---------------- fused sort + agg1 + gemm2 (block = 128-node bucket) -------
// Phase S: ONE pass over epack: stage pay(u32)+d7(u8) to LDS + LDS hist
//          from registers -> scan (off written for agg2) -> scatter from
//          LDS to lsort -> stream lsort to esort.
// Phase A: group-per-node (16 waves x 8 groups = 128 nodes); per edge:
//          8-lane-broadcast ds_read of lsort + 16B Wh1 gather + 8 fma.
// Phase G: Wh2[128,64] = h1_tile @ W2 + b2 (fp16 A exact, hi/lo W2).
__global__ __launch_bounds__(1024) void sort_agg1_gemm2(
        const int* __restrict__ gcur,
        const int2* __restrict__ epack,
        const _Float16* __restrict__ Wh1,
        const float* __restrict__ W2, const float* __restrict__ b2,
        unsigned int* __restrict__ esort, int* __restrict__ off,
        _Float16* __restrict__ outB) {
    __shared__ unsigned int lsort[SLOTC];     // 13.5 KB
    __shared__ int cnt[128];
    __shared__ int start[128];
    __shared__ int wsum[2];
    __shared__ _Float16 w2hi[64 * RS2];       // 9.2 KB
    __shared__ _Float16 w2lo[64 * RS2];       // 9.2 KB
    __shared__ union AU {                     // 18 KB
        struct { unsigned int pay[SLOTC]; unsigned char d7[SLOTC]; } s;
        _Float16 hs[128 * RS2];               // h1 tile (phase A/G)
    } u;
    const int tid = threadIdx.x;
    const int bkt = blockIdx.x;
    const int beg = bkt * SLOTC;
    const int n = min(gcur[bkt], SLOTC);

    // stage W2 transposed hi/lo (overlaps epack stage)
    for (int i = tid; i < 64 * HID; i += 1024) {
        int nn = i >> 6, k = i & 63;
        float wv = W2[k * 64 + nn];
        _Float16 hi = (_Float16)wv;
        w2hi[nn * RS2 + k] = hi;
        w2lo[nn * RS2 + k] = (_Float16)(wv - (float)hi);
    }
    if (tid < 128) cnt[tid] = 0;
    __syncthreads();

    // single pass over epack: stage to LDS + hist from registers
    for (int e = tid; e < n; e += 1024) {
        int2 pk = epack[beg + e];
        int d7 = (pk.x >> 16) & 127;
        unsigned short hw = __half_as_ushort(__float2half(__int_as_float(pk.y)));
        u.s.pay[e] = (unsigned int)(pk.x & 0xffff) | ((unsigned int)hw << 16);
        u.s.d7[e] = (unsigned char)d7;
        atomicAdd(&cnt[d7], 1);
    }
    __syncthreads();

    int orig = 0, incl = 0;
    if (tid < 128) {
        orig = cnt[tid];
        int v = orig;
        for (int o = 1; o < 64; o <<= 1) {
            int t = __shfl_up(v, o);
            if ((tid & 63) >= o) v += t;
        }
        if ((tid & 63) == 63) wsum[tid >> 6] = v;
        incl = v;
    }
    __syncthreads();
    if (tid < 128) {
        if (tid >= 64) incl += wsum[0];
        int excl = incl - orig;
        start[tid] = excl;
        off[bkt * 129 + tid] = beg + excl;
        if (tid == 127) off[bkt * 129 + 128] = beg + incl;
        cnt[tid] = 0;                          // reuse as cursor
    }
    __syncthreads();

    // scatter from LDS stage to lsort
    for (int e = tid; e < n; e += 1024) {
        int d7 = u.s.d7[e];
        int pos = atomicAdd(&cnt[d7], 1);
        int idx = start[d7] + pos;
        if (idx < SLOTC)
            lsort[idx] = u.s.pay[e];
    }
    __syncthreads();

    // stream to esort for agg2 (coalesced); lsort read-only from here on
    for (int i = tid; i < n; i += 1024)
        esort[beg + i] = lsort[i];

    // Phase A: aggregate from LDS. group nl handles local node nl.
    // (writes u.hs — safe: u.s last read before the scatter sync)
    {
        const int lane = tid & 63;
        const int g = lane >> 3, p = lane & 7;
        const int nl = (tid >> 6) * 8 + g;    // 0..127
        const int lbeg = start[nl];
        const int deg = cnt[nl];              // cursor == bin count
        float acc[8] = {0, 0, 0, 0, 0, 0, 0, 0};
        const int lend = min(lbeg + deg, SLOTC);
        for (int e = lbeg; e < lend; ++e) {
            const unsigned int pe = lsort[e]; // 8-lane broadcast read
            const float w =
                __half2float(__ushort_as_half((unsigned short)(pe >> 16)));
            half8 row = *(const half8*)(Wh1 + (size_t)(pe & 0xffff) * HID + p * 8);
#pragma unroll
            for (int j = 0; j < 8; ++j)
                acc[j] = fmaf((float)row[j], w, acc[j]);
        }
        const float inv = 1.0f / fmaxf((float)deg, 1.0f);
        half8 hv;
#pragma unroll
        for (int j = 0; j < 8; ++j) {
            float t = acc[j] * inv;
            t = t >= 0.0f ? t : NEG_SLOPE * t;   // leaky relu
            hv[j] = (_Float16)t;
        }
        *(half8*)&u.hs[nl * RS2 + p * 8] = hv;
    }
    __syncthreads();

    // Phase G: gemm2. wave w: row-tile r = w>>1 (16 rows), col half ch = w&1.
    {
        const int lane = tid & 63, wid = tid >> 6;
        const int q = lane >> 4, c = lane & 15;
        const int r = wid >> 1, ch = wid & 1;
        floatx4 acc0 = {b2[ch * 32 + c], b2[ch * 32 + c],
                        b2[ch * 32 + c], b2[ch * 32 + c]};
        floatx4 acc1 = {b2[ch * 32 + 16 + c], b2[ch * 32 + 16 + c],
                        b2[ch * 32 + 16 + c], b2[ch * 32 + 16 + c]};
#pragma unroll
        for (int ks = 0; ks < 2; ++ks) {
            const int kb = ks * 32 + q * 8;
            half8 a = *(const half8*)&u.hs[(r * 16 + c) * RS2 + kb];
            half8 bh0 = *(const half8*)&w2hi[(ch * 32 + c) * RS2 + kb];
            half8 bl0 = *(const half8*)&w2lo[(ch * 32 + c) * RS2 + kb];
            half8 bh1 = *(const half8*)&w2hi[(ch * 32 + 16 + c) * RS2 + kb];
            half8 bl1 = *(const half8*)&w2lo[(ch * 32 + 16 + c) * RS2 + kb];
            acc0 = __builtin_amdgcn_mfma_f32_16x16x32_f16(a, bh0, acc0, 0, 0, 0);
            acc0 = __builtin_amdgcn_mfma_f32_16x16x32_f16(a, bl0, acc0, 0, 0, 0);
            acc1 = __builtin_amdgcn_mfma_f32_16x16x32_f16(a, bh1, acc1, 0, 0, 0);
            acc1 = __builtin_amdgcn_mfma_f32_16x16x32_f16(a, bl1, acc1, 0, 0, 0);
        }
        const int rowb = bkt * 128 + r * 16 + q * 4;
#pragma unroll
        for (int rr = 0; rr < 4; ++rr) {
            if (rowb + rr < N_NODES) {
                _Float16* op = outB + (size_t)(rowb + rr) * HID + ch * 32 + c;
                op[0]  = (_Float16)acc0[rr];
                op[16] = (_Float16)acc1[rr];
            }
        }
    }
}

// ---------------- agg2 (group-per-node, shfl payloads) ----------------------
__global__ __launch_bounds__(256) void agg2_k(const _Float16* __restrict__ Wh,
                                              const int* __restrict__ off,
                                              const unsigned int* __restrict__ es,
                                              float* __restrict__ out) {
    const int tid = threadIdx.x;
    const int lane = tid & 63;
    const int wid = tid >> 6;
    const int g = lane >> 3, p = lane & 7;
    const int node = blockIdx.x * 32 + wid * 8 + g;
    const bool valid = node < N_NODES;
    int beg = 0, end = 0;
    if (valid) {
        const int o = (node >> 7) * 129 + (node & 127);
        beg = off[o];
        end = off[o + 1];
    }
    const int deg = end - beg;

    unsigned int pld[5];
#pragma unroll
    for (int c = 0; c < 5; ++c) {
        int e = beg + c * 8 + p;
        pld[c] = (e < end) ? es[e] : 0u;
    }

    int mdeg = deg;
#pragma unroll
    for (int mask = 8; mask <= 32; mask <<= 1)
        mdeg = max(mdeg, __shfl_xor(mdeg, mask));

    float acc[8] = {0, 0, 0, 0, 0, 0, 0, 0};
#pragma unroll
    for (int c = 0; c < 5; ++c) {
        if (c * 8 >= mdeg) break;
#pragma unroll
        for (int s = 0; s < 8; ++s) {
            const unsigned int pe = __shfl(pld[c], (g << 3) | s);
            const bool act = beg + c * 8 + s < end;
            const int srow = act ? (int)(pe & 0xffff) : 0;   // row 0: L1-hot
            const float w = act
                ? __half2float(__ushort_as_half((unsigned short)(pe >> 16)))
                : 0.0f;
            half8 row = *(const half8*)(Wh + (size_t)srow * HID + p * 8);
#pragma unroll
            for (int j = 0; j < 8; ++j)
                acc[j] = fmaf((float)row[j], w, acc[j]);
        }
    }
    for (int e = beg + 40; e < end; ++e) {    // rare tail (P ~ 8e-4)
        const unsigned int pe = es[e];
        const float w =
            __half2float(__ushort_as_half((unsigned short)(pe >> 16)));
        half8 row = *(const half8*)(Wh + (size_t)(pe & 0xffff) * HID + p * 8);
#pragma unroll
        for (int j = 0; j < 8; ++j)
            acc[j] = fmaf((float)row[j], w, acc[j]);
    }

    if (valid) {
        const float inv = 1.0f / fmaxf((float)deg, 1.0f);
        float4* op = (float4*)(out + (size_t)node * HID + p * 8);
        op[0] = make_float4(acc[0] * inv, acc[1] * inv, acc[2] * inv, acc[3] * inv);
        op[1] = make_float4(acc[4] * inv, acc[5] * inv, acc[6] * inv, acc[7] * inv);
    }
}

extern "C" void kernel_launch(void* const* d_in, const int* in_sizes, int n_in,
                              void* d_out, int out_size, void* d_ws, size_t ws_size,
                              hipStream_t stream) {
    const float* x  = (const float*)d_in[0];
    const float* ew = (const float*)d_in[1];
    const float* W1 = (const float*)d_in[2];
    const float* b1 = (const float*)d_in[3];
    const float* W2 = (const float*)d_in[4];
    const float* b2 = (const float*)d_in[5];
    const int* src  = (const int*)d_in[6];
    const int* dst  = (const int*)d_in[7];
    float* out = (float*)d_out;

    const int NH = N_NODES * HID;
    const int ES = NBB * SLOTC;                             // 1,351,296

    // ws layout (~29 MB):
    // gcur(400) | off(391*129+1 pad 50448) | esort u32 | epack int2 |
    // bufA (Wh1) | bufB (Wh2)
    int* gcur = (int*)d_ws;                                 // 391 (+pad 400)
    int* off  = gcur + 400;                                 // 50440 (+pad)
    unsigned int* esort = (unsigned int*)(off + 50448);     // ES u32 (5.4 MB)
    int2* epack = (int2*)(esort + ES);                      // ES int2 (10.8 MB)
    _Float16* bufA = (_Float16*)(epack + ES);               // Wh1 (6.4 MB)
    _Float16* bufB = bufA + NH;                             // Wh2 (6.4 MB)

    const int agg2Blocks = (N_NODES + 31) / 32;             // 1563

    hipMemsetAsync(gcur, 0, 400 * sizeof(int), stream);

    // fill + gemm1 fused (independent inputs)
    fill_gemm1<<<FILL_BLOCKS + GEMM_BLOCKS, 1024, 0, stream>>>(
        src, dst, ew, gcur, epack, x, W1, b1, bufA);

    // sort + agg1 + gemm2 fused (block = 128-node bucket) -> esort/off + Wh2
    sort_agg1_gemm2<<<NBB, 1024, 0, stream>>>(
        gcur, epack, bufA, W2, b2, esort, off, bufB);

    // final aggregation
    agg2_k<<<agg2Blocks, 256, 0, stream>>>(bufB, off, esort, out);
}

// Round 5
// 74.228 us; speedup vs baseline: 1.5444x; 1.0360x over previous
//
#include <hip/hip_runtime.h>
#include <hip/hip_fp16.h>

// WordGraphNet fp32. Round 18: bucket-sorted coalesced fill writes.
// R17 (coop mega-kernel) failed correctness (stale/zero output) -> reverted
// to R16 structure. R16's largest controllable dispatch is fill_gemm1
// (~30us): 1.2M scattered 8B epack stores -> ~3-4x HBM write amplification
// (R15 measured 58MB WRITE vs ~17MB ideal). Fix: block-sort the 8192 edges
// by coarse bucket in LDS (hist -> 391-bin scan -> LDS scatter), then write
// bucket-contiguous runs (~21 edges) coalesced. Weight converted to fp16 at
// fill (same conversion as before, just earlier): global edge record is now
// epay u32 (src|hw) + ed7 u8 = 5B instead of int2 8B -> sort kernel reads
// 6.8MB not 10.8MB and skips the cvt.
// Pipeline: memset(1.6KB) | fill+gemm1 | sort+agg1+gemm2 | agg2.

#define N_NODES 50000
#define N_EDGES 1200000
#define IN_SIZE 128
#define HID 64
#define NEG_SLOPE 0.01f
#define NBB 391           // buckets of 128 nodes: ceil(50000/128)
#define SLOTC 3456        // slots/bucket (mean 3070, sigma 55 -> +7 sigma)
#define FILL_EPB 8192
#define FILL_BLOCKS ((N_EDGES + FILL_EPB - 1) / FILL_EPB)   // 147
#define GEMM_BLOCKS ((N_NODES + 255) / 256)                 // 196
#define RS2 (HID + 8)     // padded LDS row stride (72 halves = 144B)

typedef _Float16 half8 __attribute__((ext_vector_type(8)));
typedef float floatx4 __attribute__((ext_vector_type(4)));

// ---------------- MFMA GEMM body (1024 thr, 256 rows/blk), fp32 A -----------
template <int K>
__device__ __forceinline__ void gemm_body(int blk,
                                          const float* __restrict__ A,
                                          const float* __restrict__ W,
                                          const float* __restrict__ b,
                                          _Float16* __restrict__ out,
                                          _Float16* wthi, _Float16* wtlo) {
    constexpr int RS = K + 8;
    const int tid = threadIdx.x;
    for (int i = tid; i < 64 * K; i += 1024) {
        int n = i / K, k = i % K;
        float wv = W[k * 64 + n];
        _Float16 hi = (_Float16)wv;
        wthi[n * RS + k] = hi;
        wtlo[n * RS + k] = (_Float16)(wv - (float)hi);
    }
    __syncthreads();

    const int lane = tid & 63;
    const int wid = tid >> 6;
    const int q = lane >> 4, c = lane & 15;

    int arow = blk * 256 + wid * 16 + c;
    int lrow = min(arow, N_NODES - 1);
    const float* ap = A + (size_t)lrow * K + q * 8;

    floatx4 acc0 = {b[c],      b[c],      b[c],      b[c]};
    floatx4 acc1 = {b[c + 16], b[c + 16], b[c + 16], b[c + 16]};
    floatx4 acc2 = {b[c + 32], b[c + 32], b[c + 32], b[c + 32]};
    floatx4 acc3 = {b[c + 48], b[c + 48], b[c + 48], b[c + 48]};

#pragma unroll
    for (int ks = 0; ks < K / 32; ++ks) {
        float4 f0 = ((const float4*)(ap + ks * 32))[0];
        float4 f1 = ((const float4*)(ap + ks * 32))[1];
        float fv[8] = {f0.x, f0.y, f0.z, f0.w, f1.x, f1.y, f1.z, f1.w};
        half8 ahi, alo;
#pragma unroll
        for (int j = 0; j < 8; ++j) {
            _Float16 h = (_Float16)fv[j];
            ahi[j] = h;
            alo[j] = (_Float16)(fv[j] - (float)h);
        }
        const int kb = ks * 32 + q * 8;
        half8 bh0 = *(const half8*)&wthi[(c     ) * RS + kb];
        half8 bl0 = *(const half8*)&wtlo[(c     ) * RS + kb];
        half8 bh1 = *(const half8*)&wthi[(c + 16) * RS + kb];
        half8 bl1 = *(const half8*)&wtlo[(c + 16) * RS + kb];
        half8 bh2 = *(const half8*)&wthi[(c + 32) * RS + kb];
        half8 bl2 = *(const half8*)&wtlo[(c + 32) * RS + kb];
        half8 bh3 = *(const half8*)&wthi[(c + 48) * RS + kb];
        half8 bl3 = *(const half8*)&wtlo[(c + 48) * RS + kb];
        acc0 = __builtin_amdgcn_mfma_f32_16x16x32_f16(ahi, bh0, acc0, 0, 0, 0);
        acc0 = __builtin_amdgcn_mfma_f32_16x16x32_f16(ahi, bl0, acc0, 0, 0, 0);
        acc0 = __builtin_amdgcn_mfma_f32_16x16x32_f16(alo, bh0, acc0, 0, 0, 0);
        acc1 = __builtin_amdgcn_mfma_f32_16x16x32_f16(ahi, bh1, acc1, 0, 0, 0);
        acc1 = __builtin_amdgcn_mfma_f32_16x16x32_f16(ahi, bl1, acc1, 0, 0, 0);
        acc1 = __builtin_amdgcn_mfma_f32_16x16x32_f16(alo, bh1, acc1, 0, 0, 0);
        acc2 = __builtin_amdgcn_mfma_f32_16x16x32_f16(ahi, bh2, acc2, 0, 0, 0);
        acc2 = __builtin_amdgcn_mfma_f32_16x16x32_f16(ahi, bl2, acc2, 0, 0, 0);
        acc2 = __builtin_amdgcn_mfma_f32_16x16x32_f16(alo, bh2, acc2, 0, 0, 0);
        acc3 = __builtin_amdgcn_mfma_f32_16x16x32_f16(ahi, bh3, acc3, 0, 0, 0);
        acc3 = __builtin_amdgcn_mfma_f32_16x16x32_f16(ahi, bl3, acc3, 0, 0, 0);
        acc3 = __builtin_amdgcn_mfma_f32_16x16x32_f16(alo, bh3, acc3, 0, 0, 0);
    }

    int rowb = blk * 256 + wid * 16 + q * 4;
#pragma unroll
    for (int r = 0; r < 4; ++r) {
        if (rowb + r < N_NODES) {
            _Float16* op = out + (size_t)(rowb + r) * HID + c;
            op[0]  = (_Float16)acc0[r];
            op[16] = (_Float16)acc1[r];
            op[32] = (_Float16)acc2[r];
            op[48] = (_Float16)acc3[r];
        }
    }
}

// ---------------- fill body v5: LDS bucket-sort, coalesced write-out --------
struct FillLds {
    unsigned int spay[FILL_EPB];      // 32 KB: src | hw<<16, sorted by bucket
    unsigned short saux[FILL_EPB];    // 16 KB: d7 | bucket<<7
    int lhist[NBB];                   // hist, then scatter cursor
    int lbase[NBB];                   // global base - local start
    int lstart[NBB];                  // local exclusive start
    int wsum[8];
};

__device__ __forceinline__ void fill_body(int blk,
                                          const int* __restrict__ src,
                                          const int* __restrict__ dst,
                                          const float* __restrict__ ew,
                                          int* __restrict__ gcur,
                                          unsigned int* __restrict__ epay,
                                          unsigned char* __restrict__ ed7,
                                          FillLds& f) {
    const int tid = threadIdx.x;
    const int e0 = blk * FILL_EPB;
    const int nblk = min(FILL_EPB, N_EDGES - e0);
    if (tid < NBB) f.lhist[tid] = 0;

    const int g0 = e0 + 4 * tid, g1 = g0 + 4096;
    const bool a0 = g0 < N_EDGES, a1 = g1 < N_EDGES;
    int4 d0 = {0,0,0,0}, d1 = {0,0,0,0}, s0 = {0,0,0,0}, s1 = {0,0,0,0};
    float4 w0 = {0,0,0,0}, w1 = {0,0,0,0};
    if (a0) { d0 = *(const int4*)(dst + g0); s0 = *(const int4*)(src + g0);
              w0 = *(const float4*)(ew + g0); }
    if (a1) { d1 = *(const int4*)(dst + g1); s1 = *(const int4*)(src + g1);
              w1 = *(const float4*)(ew + g1); }
    __syncthreads();

    if (a0) { atomicAdd(&f.lhist[d0.x >> 7], 1); atomicAdd(&f.lhist[d0.y >> 7], 1);
              atomicAdd(&f.lhist[d0.z >> 7], 1); atomicAdd(&f.lhist[d0.w >> 7], 1); }
    if (a1) { atomicAdd(&f.lhist[d1.x >> 7], 1); atomicAdd(&f.lhist[d1.y >> 7], 1);
              atomicAdd(&f.lhist[d1.z >> 7], 1); atomicAdd(&f.lhist[d1.w >> 7], 1); }
    __syncthreads();

    // block-local exclusive scan over 391 bins + global reservation
    int orig = 0, v = 0;
    if (tid < NBB) {
        orig = f.lhist[tid];
        v = orig;
        for (int o = 1; o < 64; o <<= 1) {
            int t = __shfl_up(v, o);
            if ((tid & 63) >= o) v += t;
        }
        if ((tid & 63) == 63 || tid == NBB - 1) f.wsum[tid >> 6] = v;
    }
    __syncthreads();
    if (tid < NBB) {
        int w = tid >> 6;
        int incl = v;
        for (int k = 0; k < w; ++k) incl += f.wsum[k];
        int excl = incl - orig;
        f.lstart[tid] = excl;
        int gb = orig ? atomicAdd(&gcur[tid], orig) : 0;
        f.lbase[tid] = tid * SLOTC + gb - excl;   // so gidx = lbase[b] + i
        f.lhist[tid] = 0;                         // reuse as scatter cursor
    }
    __syncthreads();

    // scatter to LDS stage, sorted by bucket (weight -> fp16 here)
    const int dd0[4] = {d0.x, d0.y, d0.z, d0.w};
    const int ss0[4] = {s0.x, s0.y, s0.z, s0.w};
    const float ww0[4] = {w0.x, w0.y, w0.z, w0.w};
    const int dd1[4] = {d1.x, d1.y, d1.z, d1.w};
    const int ss1[4] = {s1.x, s1.y, s1.z, s1.w};
    const float ww1[4] = {w1.x, w1.y, w1.z, w1.w};
    if (a0) {
#pragma unroll
        for (int j = 0; j < 4; ++j) {
            int d = dd0[j], b = d >> 7;
            unsigned short hw = __half_as_ushort(__float2half(ww0[j]));
            int pos = f.lstart[b] + atomicAdd(&f.lhist[b], 1);
            f.spay[pos] = (unsigned int)(ss0[j] & 0xffff) | ((unsigned int)hw << 16);
            f.saux[pos] = (unsigned short)((d & 127) | (b << 7));
        }
    }
    if (a1) {
#pragma unroll
        for (int j = 0; j < 4; ++j) {
            int d = dd1[j], b = d >> 7;
            unsigned short hw = __half_as_ushort(__float2half(ww1[j]));
            int pos = f.lstart[b] + atomicAdd(&f.lhist[b], 1);
            f.spay[pos] = (unsigned int)(ss1[j] & 0xffff) | ((unsigned int)hw << 16);
            f.saux[pos] = (unsigned short)((d & 127) | (b << 7));
        }
    }
    __syncthreads();

    // write out bucket-contiguous runs (coalesced within run)
    for (int i = tid; i < nblk; i += 1024) {
        int aux = f.saux[i];
        int b = aux >> 7;
        int gi = f.lbase[b] + i;
        if (gi < (b + 1) * SLOTC) {            // 7-sigma guard, never taken
            epay[gi] = f.spay[i];
            ed7[gi] = (unsigned char)(aux & 127);
        }
    }
}

// ---------------- fused dispatch: fill (0..146) + gemm1 (147..342) ----------
__global__ __launch_bounds__(1024) void fill_gemm1(const int* __restrict__ src,
                                                   const int* __restrict__ dst,
                                                   const float* __restrict__ ew,
                                                   int* __restrict__ gcur,
                                                   unsigned int* __restrict__ epay,
                                                   unsigned char* __restrict__ ed7,
                                                   const float* __restrict__ x,
                                                   const float* __restrict__ W1,
                                                   const float* __restrict__ b1,
                                                   _Float16* __restrict__ outA) {
    __shared__ union SU {
        FillLds f;                                    // ~53 KB
        struct { _Float16 hi[64 * (IN_SIZE + 8)];
                 _Float16 lo[64 * (IN_SIZE + 8)]; } g;  // 34 KB
    } u;
    if (blockIdx.x < FILL_BLOCKS)
        fill_body(blockIdx.x, src, dst, ew, gcur, epay, ed7, u.f);
    else
        gemm_body<IN_SIZE>(blockIdx.x - FILL_BLOCKS, x, W1, b1, outA,
                           u.g.hi, u.g.lo);
}

// ---------------- fused sort + agg1 + gemm2 (block = 128-node bucket) -------
// Phase S: one pass over epay/ed7 (5B/edge): stage + LDS hist -> scan (off
//          written for agg2) -> scatter to lsort -> stream lsort to esort.
// Phase A: group-per-node (16 waves x 8 groups = 128 nodes); per edge:
//          8-lane-broadcast ds_read of lsort + 16B Wh1 gather + 8 fma.
// Phase G: Wh2[128,64] = h1_tile @ W2 + b2 (fp16 A exact, hi/lo W2).
__global__ __launch_bounds__(1024) void sort_agg1_gemm2(
        const int* __restrict__ gcur,
        const unsigned int* __restrict__ epay,
        const unsigned char* __restrict__ ed7,
        const _Float16* __restrict__ Wh1,
        const float* __restrict__ W2, const float* __restrict__ b2,
        unsigned int* __restrict__ esort, int* __restrict__ off,
        _Float16* __restrict__ outB) {
    __shared__ unsigned int lsort[SLOTC];     // 13.5 KB
    __shared__ int cnt[128];
    __shared__ int start[128];
    __shared__ int wsum[2];
    __shared__ _Float16 w2hi[64 * RS2];       // 9.2 KB
    __shared__ _Float16 w2lo[64 * RS2];       // 9.2 KB
    __shared__ union AU {                     // 18 KB
        struct { unsigned int pay[SLOTC]; unsigned char d7[SLOTC]; } s;
        _Float16 hs[128 * RS2];               // h1 tile (phase A/G)
    } u;
    const int tid = threadIdx.x;
    const int bkt = blockIdx.x;
    const int beg = bkt * SLOTC;
    const int n = min(gcur[bkt], SLOTC);

    // stage W2 transposed hi/lo (overlaps edge stage)
    for (int i = tid; i < 64 * HID; i += 1024) {
        int nn = i >> 6, k = i & 63;
        float wv = W2[k * 64 + nn];
        _Float16 hi = (_Float16)wv;
        w2hi[nn * RS2 + k] = hi;
        w2lo[nn * RS2 + k] = (_Float16)(wv - (float)hi);
    }
    if (tid < 128) cnt[tid] = 0;
    __syncthreads();

    // single pass over epay/ed7: stage to LDS + hist
    for (int e = tid; e < n; e += 1024) {
        int d7 = ed7[beg + e];
        u.s.pay[e] = epay[beg + e];
        u.s.d7[e] = (unsigned char)d7;
        atomicAdd(&cnt[d7], 1);
    }
    __syncthreads();

    int orig = 0, incl = 0;
    if (tid < 128) {
        orig = cnt[tid];
        int v = orig;
        for (int o = 1; o < 64; o <<= 1) {
            int t = __shfl_up(v, o);
            if ((tid & 63) >= o) v += t;
        }
        if ((tid & 63) == 63) wsum[tid >> 6] = v;
        incl = v;
    }
    __syncthreads();
    if (tid < 128) {
        if (tid >= 64) incl += wsum[0];
        int excl = incl - orig;
        start[tid] = excl;
        off[bkt * 129 + tid] = beg + excl;
        if (tid == 127) off[bkt * 129 + 128] = beg + incl;
        cnt[tid] = 0;                          // reuse as cursor
    }
    __syncthreads();

    // scatter from LDS stage to lsort
    for (int e = tid; e < n; e += 1024) {
        int d7 = u.s.d7[e];
        int pos = atomicAdd(&cnt[d7], 1);
        int idx = start[d7] + pos;
        if (idx < SLOTC)
            lsort[idx] = u.s.pay[e];
    }
    __syncthreads();

    // stream to esort for agg2 (coalesced); lsort read-only from here on
    for (int i = tid; i < n; i += 1024)
        esort[beg + i] = lsort[i];

    // Phase A: aggregate from LDS. group nl handles local node nl.
    // (writes u.hs — safe: u.s last read before the scatter sync)
    {
        const int lane = tid & 63;
        const int g = lane >> 3, p = lane & 7;
        const int nl = (tid >> 6) * 8 + g;    // 0..127
        const int lbeg = start[nl];
        const int deg = cnt[nl];              // cursor == bin count
        float acc[8] = {0, 0, 0, 0, 0, 0, 0, 0};
        const int lend = min(lbeg + deg, SLOTC);
        for (int e = lbeg; e < lend; ++e) {
            const unsigned int pe = lsort[e]; // 8-lane broadcast read
            const float w =
                __half2float(__ushort_as_half((unsigned short)(pe >> 16)));
            half8 row = *(const half8*)(Wh1 + (size_t)(pe & 0xffff) * HID + p * 8);
#pragma unroll
            for (int j = 0; j < 8; ++j)
                acc[j] = fmaf((float)row[j], w, acc[j]);
        }
        const float inv = 1.0f / fmaxf((float)deg, 1.0f);
        half8 hv;
#pragma unroll
        for (int j = 0; j < 8; ++j) {
            float t = acc[j] * inv;
            t = t >= 0.0f ? t : NEG_SLOPE * t;   // leaky relu
            hv[j] = (_Float16)t;
        }
        *(half8*)&u.hs[nl * RS2 + p * 8] = hv;
    }
    __syncthreads();

    // Phase G: gemm2. wave w: row-tile r = w>>1 (16 rows), col half ch = w&1.
    {
        const int lane = tid & 63, wid = tid >> 6;
        const int q = lane >> 4, c = lane & 15;
        const int r = wid >> 1, ch = wid & 1;
        floatx4 acc0 = {b2[ch * 32 + c], b2[ch * 32 + c],
                        b2[ch * 32 + c], b2[ch * 32 + c]};
        floatx4 acc1 = {b2[ch * 32 + 16 + c], b2[ch * 32 + 16 + c],
                        b2[ch * 32 + 16 + c], b2[ch * 32 + 16 + c]};
#pragma unroll
        for (int ks = 0; ks < 2; ++ks) {
            const int kb = ks * 32 + q * 8;
            half8 a = *(const half8*)&u.hs[(r * 16 + c) * RS2 + kb];
            half8 bh0 = *(const half8*)&w2hi[(ch * 32 + c) * RS2 + kb];
            half8 bl0 = *(const half8*)&w2lo[(ch * 32 + c) * RS2 + kb];
            half8 bh1 = *(const half8*)&w2hi[(ch * 32 + 16 + c) * RS2 + kb];
            half8 bl1 = *(const half8*)&w2lo[(ch * 32 + 16 + c) * RS2 + kb];
            acc0 = __builtin_amdgcn_mfma_f32_16x16x32_f16(a, bh0, acc0, 0, 0, 0);
            acc0 = __builtin_amdgcn_mfma_f32_16x16x32_f16(a, bl0, acc0, 0, 0, 0);
            acc1 = __builtin_amdgcn_mfma_f32_16x16x32_f16(a, bh1, acc1, 0, 0, 0);
            acc1 = __builtin_amdgcn_mfma_f32_16x16x32_f16(a, bl1, acc1, 0, 0, 0);
        }
        const int rowb = bkt * 128 + r * 16 + q * 4;
#pragma unroll
        for (int rr = 0; rr < 4; ++rr) {
            if (rowb + rr < N_NODES) {
                _Float16* op = outB + (size_t)(rowb + rr) * HID + ch * 32 + c;
                op[0]  = (_Float16)acc0[rr];
                op[16] = (_Float16)acc1[rr];
            }
        }
    }
}

// ---------------- agg2 (group-per-node, shfl payloads) ----------------------
__global__ __launch_bounds__(256) void agg2_k(const _Float16* __restrict__ Wh,
                                              const int* __restrict__ off,
                                              const unsigned int* __restrict__ es,
                                              float* __restrict__ out) {
    const int tid = threadIdx.x;
    const int lane = tid & 63;
    const int wid = tid >> 6;
    const int g = lane >> 3, p = lane & 7;
    const int node = blockIdx.x * 32 + wid * 8 + g;
    const bool valid = node < N_NODES;
    int beg = 0, end = 0;
    if (valid) {
        const int o = (node >> 7) * 129 + (node & 127);
        beg = off[o];
        end = off[o + 1];
    }
    const int deg = end - beg;

    unsigned int pld[5];
#pragma unroll
    for (int c = 0; c < 5; ++c) {
        int e = beg + c * 8 + p;
        pld[c] = (e < end) ? es[e] : 0u;
    }

    int mdeg = deg;
#pragma unroll
    for (int mask = 8; mask <= 32; mask <<= 1)
        mdeg = max(mdeg, __shfl_xor(mdeg, mask));

    float acc[8] = {0, 0, 0, 0, 0, 0, 0, 0};
#pragma unroll
    for (int c = 0; c < 5; ++c) {
        if (c * 8 >= mdeg) break;
#pragma unroll
        for (int s = 0; s < 8; ++s) {
            const unsigned int pe = __shfl(pld[c], (g << 3) | s);
            const bool act = beg + c * 8 + s < end;
            const int srow = act ? (int)(pe & 0xffff) : 0;   // row 0: L1-hot
            const float w = act
                ? __half2float(__ushort_as_half((unsigned short)(pe >> 16)))
                : 0.0f;
            half8 row = *(const half8*)(Wh + (size_t)srow * HID + p * 8);
#pragma unroll
            for (int j = 0; j < 8; ++j)
                acc[j] = fmaf((float)row[j], w, acc[j]);
        }
    }
    for (int e = beg + 40; e < end; ++e) {    // rare tail (P ~ 8e-4)
        const unsigned int pe = es[e];
        const float w =
            __half2float(__ushort_as_half((unsigned short)(pe >> 16)));
        half8 row = *(const half8*)(Wh + (size_t)(pe & 0xffff) * HID + p * 8);
#pragma unroll
        for (int j = 0; j < 8; ++j)
            acc[j] = fmaf((float)row[j], w, acc[j]);
    }

    if (valid) {
        const float inv = 1.0f / fmaxf((float)deg, 1.0f);
        float4* op = (float4*)(out + (size_t)node * HID + p * 8);
        op[0] = make_float4(acc[0] * inv, acc[1] * inv, acc[2] * inv, acc[3] * inv);
        op[1] = make_float4(acc[4] * inv, acc[5] * inv, acc[6] * inv, acc[7] * inv);
    }
}

extern "C" void kernel_launch(void* const* d_in, const int* in_sizes, int n_in,
                              void* d_out, int out_size, void* d_ws, size_t ws_size,
                              hipStream_t stream) {
    const float* x  = (const float*)d_in[0];
    const float* ew = (const float*)d_in[1];
    const float* W1 = (const float*)d_in[2];
    const float* b1 = (const float*)d_in[3];
    const float* W2 = (const float*)d_in[4];
    const float* b2 = (const float*)d_in[5];
    const int* src  = (const int*)d_in[6];
    const int* dst  = (const int*)d_in[7];
    float* out = (float*)d_out;

    const int NH = N_NODES * HID;
    const int ES = NBB * SLOTC;                             // 1,351,296

    // ws layout (~25 MB):
    // gcur(400) | off(391*129+1 pad 50448) | esort u32 | epay u32 | ed7 u8 |
    // bufA (Wh1) | bufB (Wh2)
    int* gcur = (int*)d_ws;                                 // 391 (+pad 400)
    int* off  = gcur + 400;                                 // 50440 (+pad)
    unsigned int* esort = (unsigned int*)(off + 50448);     // ES u32 (5.4 MB)
    unsigned int* epay = esort + ES;                        // ES u32 (5.4 MB)
    unsigned char* ed7 = (unsigned char*)(epay + ES);       // ES u8  (1.35 MB)
    _Float16* bufA = (_Float16*)(ed7 + ES);                 // Wh1 (6.4 MB)
    _Float16* bufB = bufA + NH;                             // Wh2 (6.4 MB)

    const int agg2Blocks = (N_NODES + 31) / 32;             // 1563

    hipMemsetAsync(gcur, 0, 400 * sizeof(int), stream);

    // fill + gemm1 fused (independent inputs)
    fill_gemm1<<<FILL_BLOCKS + GEMM_BLOCKS, 1024, 0, stream>>>(
        src, dst, ew, gcur, epay, ed7, x, W1, b1, bufA);

    // sort + agg1 + gemm2 fused (block = 128-node bucket) -> esort/off + Wh2
    sort_agg1_gemm2<<<NBB, 1024, 0, stream>>>(
        gcur, epay, ed7, bufA, W2, b2, esort, off, bufB);

    // final aggregation
    agg2_k<<<agg2Blocks, 256, 0, stream>>>(bufB, off, esort, out);
}